// Round 11
// baseline (319.988 us; speedup 1.0000x reference)
//
#include <hip/hip_runtime.h>
#include <hip/hip_bf16.h>

#define DEVFN __device__ __forceinline__

typedef __attribute__((ext_vector_type(8))) short short8;
typedef __attribute__((ext_vector_type(4))) short short4v;
typedef __attribute__((ext_vector_type(4))) float f32x4;

#define MFMA(a,b,c) __builtin_amdgcn_mfma_f32_16x16x32_bf16((a),(b),(c),0,0,0)
#define LOG2E 1.4426950408889634f

DEVFN void gload_lds16(const __hip_bfloat16* g, __hip_bfloat16* l) {
  __builtin_amdgcn_global_load_lds((const __attribute__((address_space(1))) void*)g,
                                   (__attribute__((address_space(3))) void*)l, 16, 0, 0);
}

DEVFN float bf2f(__hip_bfloat16 h) { return __bfloat162float(h); }
DEVFN __hip_bfloat16 f2bf(float f) { return __float2bfloat16(f); }

DEVFN void store_out(float* p, float v) { *p = v; }
DEVFN void store_out(__hip_bfloat16* p, float v) { *p = f2bf(v); }

// ---------------------------------------------------------------------------
// K1: LayerNorm (fp32) -> xn split into bf16 hi + bf16 lo. One row per block.
// ---------------------------------------------------------------------------
__global__ __launch_bounds__(256) void ln_split_kernel(
    const float* __restrict__ x, const float* __restrict__ lw, const float* __restrict__ lb,
    __hip_bfloat16* __restrict__ xh, __hip_bfloat16* __restrict__ xl) {
  int row = blockIdx.x, t = threadIdx.x;
  float4 v = ((const float4*)(x + (size_t)row * 1024))[t];
  float s  = v.x + v.y + v.z + v.w;
  float ss = v.x*v.x + v.y*v.y + v.z*v.z + v.w*v.w;
  #pragma unroll
  for (int m = 1; m < 64; m <<= 1) { s += __shfl_xor(s, m); ss += __shfl_xor(ss, m); }
  __shared__ float red[8];
  int wv = t >> 6;
  if ((t & 63) == 0) { red[wv] = s; red[4 + wv] = ss; }
  __syncthreads();
  s  = red[0] + red[1] + red[2] + red[3];
  ss = red[4] + red[5] + red[6] + red[7];
  float mean = s * (1.f/1024.f);
  float var  = ss * (1.f/1024.f) - mean*mean;
  float inv  = rsqrtf(var + 1e-5f);
  float4 wv4 = ((const float4*)lw)[t];
  float4 bv4 = ((const float4*)lb)[t];
  float xv[4] = {v.x, v.y, v.z, v.w};
  float wa[4] = {wv4.x, wv4.y, wv4.z, wv4.w};
  float ba[4] = {bv4.x, bv4.y, bv4.z, bv4.w};
  union { short4v s4; __hip_bfloat16 h[4]; } uh, ul;
  #pragma unroll
  for (int j = 0; j < 4; ++j) {
    float val = (xv[j] - mean) * inv * wa[j] + ba[j];
    __hip_bfloat16 hi = f2bf(val);
    uh.h[j] = hi;
    ul.h[j] = f2bf(val - bf2f(hi));
  }
  ((short4v*)(xh + (size_t)row * 1024))[t] = uh.s4;
  ((short4v*)(xl + (size_t)row * 1024))[t] = ul.s4;
}

// ---------------------------------------------------------------------------
// K2: weight prep. Transpose fp32 [k][n] -> bf16 [n][k]; hi/lo split for Wq/Wk.
// ---------------------------------------------------------------------------
__global__ __launch_bounds__(256) void wprep_kernel(
    const float* __restrict__ Wq, const float* __restrict__ Wkv, const float* __restrict__ Wo,
    __hip_bfloat16* __restrict__ Wqk_h, __hip_bfloat16* __restrict__ Wqk_l,
    __hip_bfloat16* __restrict__ Wv, __hip_bfloat16* __restrict__ Wot) {
  __shared__ float tile[64][68];
  int bid = blockIdx.x, t = threadIdx.x;
  const float* src; int srcN, kt, nt, drow;
  __hip_bfloat16 *dh, *dl;
  if (bid < 256) {
    src = Wq; srcN = 1024; kt = bid >> 4; nt = bid & 15;
    dh = Wqk_h; dl = Wqk_l; drow = nt * 64;
  } else if (bid < 768) {
    int r = bid - 256; src = Wkv; srcN = 2048; kt = r >> 5; nt = r & 31;
    if (nt < 16) { dh = Wqk_h; dl = Wqk_l; drow = 1024 + nt * 64; }
    else         { dh = Wv;    dl = nullptr; drow = (nt - 16) * 64; }
  } else {
    int r = bid - 768; src = Wo; srcN = 1024; kt = r >> 4; nt = r & 15;
    dh = Wot; dl = nullptr; drow = nt * 64;
  }
  int lr = t >> 2, c = t & 3;
  const float* sp = src + (size_t)(kt*64 + lr) * srcN + nt*64 + c*16;
  float* tr = &tile[lr][c*16];
  ((float4*)tr)[0] = ((const float4*)sp)[0];
  ((float4*)tr)[1] = ((const float4*)sp)[1];
  ((float4*)tr)[2] = ((const float4*)sp)[2];
  ((float4*)tr)[3] = ((const float4*)sp)[3];
  __syncthreads();
  union { short8 s8[2]; __hip_bfloat16 h[16]; } hh, ll;
  #pragma unroll
  for (int e = 0; e < 16; ++e) {
    float wv = tile[c*16 + e][lr];
    __hip_bfloat16 hi = f2bf(wv);
    hh.h[e] = hi;
    ll.h[e] = f2bf(wv - bf2f(hi));
  }
  size_t doff = (size_t)(drow + lr) * 1024 + kt*64 + c*16;
  ((short8*)(dh + doff))[0] = hh.s8[0];
  ((short8*)(dh + doff))[1] = hh.s8[1];
  if (dl) {
    ((short8*)(dl + doff))[0] = ll.s8[0];
    ((short8*)(dl + doff))[1] = ll.s8[1];
  }
}

// ---------------------------------------------------------------------------
// K3: dual-precision GEMM (split-bf16, 3 MFMA) + fused per-head RMSNorm.
// v2: 2-phase double-buffered staging + counted vmcnt(8) + setprio (the
// attn-R5-validated pipeline). Q heads additionally scaled by log2e so attn
// can use exp2 directly (saves the v_mul in every __expf lowering).
// ---------------------------------------------------------------------------
__global__ __launch_bounds__(256) void gemm_dual_kernel(
    const __hip_bfloat16* __restrict__ Ah, const __hip_bfloat16* __restrict__ Al,
    const __hip_bfloat16* __restrict__ Bh, const __hip_bfloat16* __restrict__ Bl,
    __hip_bfloat16* __restrict__ Ch, __hip_bfloat16* __restrict__ Cl,
    const float* __restrict__ qg, const float* __restrict__ kg) {
  __shared__ __align__(16) __hip_bfloat16 sAh[2][4096], sAl[2][4096], sBh[2][4096], sBl[2][4096];
  const int K = 1024, N = 2048;
  int mt = blockIdx.x, nt = blockIdx.y;
  int t = threadIdx.x, w = t >> 6, l = t & 63;
  int wr = w >> 1, wc = w & 1, lr = l & 15, lk = (l >> 4) * 8;
  f32x4 acc[4][4] = {};
  // staging chunks: ci0=t (rows 0..63), ci1=256+t (rows 64..127); ko=(t&3)*8
  int r0 = t >> 2, r1 = 64 + (t >> 2), ko = (t & 3) * 8;
  int ldb0 = (w*64) * 8, ldb1 = (256 + w*64) * 8;

#define GSTAGE(B, K0) do { \
    gload_lds16(Ah + (size_t)(mt*128 + r0)*K + (K0) + ko, &sAh[B][0] + ldb0); \
    gload_lds16(Ah + (size_t)(mt*128 + r1)*K + (K0) + ko, &sAh[B][0] + ldb1); \
    gload_lds16(Al + (size_t)(mt*128 + r0)*K + (K0) + ko, &sAl[B][0] + ldb0); \
    gload_lds16(Al + (size_t)(mt*128 + r1)*K + (K0) + ko, &sAl[B][0] + ldb1); \
    gload_lds16(Bh + (size_t)(nt*128 + r0)*K + (K0) + ko, &sBh[B][0] + ldb0); \
    gload_lds16(Bh + (size_t)(nt*128 + r1)*K + (K0) + ko, &sBh[B][0] + ldb1); \
    gload_lds16(Bl + (size_t)(nt*128 + r0)*K + (K0) + ko, &sBl[B][0] + ldb0); \
    gload_lds16(Bl + (size_t)(nt*128 + r1)*K + (K0) + ko, &sBl[B][0] + ldb1); \
  } while (0)

  GSTAGE(0, 0);
  int buf = 0;
  for (int k0 = 0; k0 < K; k0 += 32) {
    if (k0 + 32 < K) {
      GSTAGE(buf ^ 1, k0 + 32);
      asm volatile("s_waitcnt vmcnt(8)" ::: "memory");  // retire cur tile; next 8 in flight
    } else {
      asm volatile("s_waitcnt vmcnt(0)" ::: "memory");
    }
    __builtin_amdgcn_s_barrier();
    const __hip_bfloat16* pAh = &sAh[buf][0];
    const __hip_bfloat16* pAl = &sAl[buf][0];
    const __hip_bfloat16* pBh = &sBh[buf][0];
    const __hip_bfloat16* pBl = &sBl[buf][0];
    short8 ah[4], al[4], bh[4], bl[4];
    #pragma unroll
    for (int m = 0; m < 4; ++m) {
      int ro = (wr*64 + m*16 + lr)*32 + lk;
      ah[m] = *(const short8*)(pAh + ro);
      al[m] = *(const short8*)(pAl + ro);
    }
    #pragma unroll
    for (int n = 0; n < 4; ++n) {
      int ro = (wc*64 + n*16 + lr)*32 + lk;
      bh[n] = *(const short8*)(pBh + ro);
      bl[n] = *(const short8*)(pBl + ro);
    }
    __builtin_amdgcn_s_setprio(1);
    #pragma unroll
    for (int m = 0; m < 4; ++m)
      #pragma unroll
      for (int n = 0; n < 4; ++n) {
        acc[m][n] = MFMA(ah[m], bh[n], acc[m][n]);
        acc[m][n] = MFMA(ah[m], bl[n], acc[m][n]);
        acc[m][n] = MFMA(al[m], bh[n], acc[m][n]);
      }
    __builtin_amdgcn_s_setprio(0);
    __builtin_amdgcn_s_barrier();
    buf ^= 1;
  }
#undef GSTAGE
  int col0 = nt*128 + wc*64;
  int head = col0 >> 6;
  const float* gamma = (head < 16) ? (qg + head*64) : (kg + (head - 16)*64);
  float qscale = (head < 16) ? LOG2E : 1.0f;   // fold log2e into q for exp2 attn
  float g[4];
  #pragma unroll
  for (int nf = 0; nf < 4; ++nf) g[nf] = gamma[nf*16 + lr];
  #pragma unroll
  for (int m = 0; m < 4; ++m) {
    #pragma unroll
    for (int r = 0; r < 4; ++r) {
      float ss2 = 0.f;
      #pragma unroll
      for (int nf = 0; nf < 4; ++nf) ss2 += acc[m][nf][r] * acc[m][nf][r];
      #pragma unroll
      for (int msk = 1; msk < 16; msk <<= 1) ss2 += __shfl_xor(ss2, msk);
      float scl = rsqrtf(ss2 * (1.f/64.f) + 1e-8f) * 8.f * qscale;
      int row = mt*128 + wr*64 + m*16 + (l >> 4)*4 + r;
      #pragma unroll
      for (int nf = 0; nf < 4; ++nf) {
        float val = acc[m][nf][r] * scl * g[nf];
        __hip_bfloat16 hi = f2bf(val);
        size_t off = (size_t)row * N + col0 + nf*16 + lr;
        Ch[off] = hi;
        Cl[off] = f2bf(val - bf2f(hi));
      }
    }
  }
}

// ---------------------------------------------------------------------------
// K4/K6: single-precision bf16 GEMM v2 — BM=128, BN=64, BK=32, 2x2 waves,
// 2-phase dbuf + counted vmcnt(3) + setprio. Grid (M/128, N/64) = 512 blocks
// = 2 blocks/CU (was 1 at 128x128) -> 2x waves/SIMD for latency hiding.
// ---------------------------------------------------------------------------
template <typename OUT_T>
__global__ __launch_bounds__(256) void gemm_single_kernel(
    const __hip_bfloat16* __restrict__ A, const __hip_bfloat16* __restrict__ Bt,
    OUT_T* __restrict__ C, int N) {
  __shared__ __align__(16) __hip_bfloat16 sA[2][4096], sB[2][2048];
  const int K = 1024;
  int mt = blockIdx.x, nt = blockIdx.y;
  int t = threadIdx.x, w = t >> 6, l = t & 63;
  int wr = w >> 1, wc = w & 1, lr = l & 15, lk = (l >> 4) * 8;
  f32x4 acc[4][2] = {};
  int rA0 = t >> 2, rA1 = 64 + (t >> 2), rB = t >> 2, ko = (t & 3) * 8;
  int ldb0 = (w*64) * 8, ldb1 = (256 + w*64) * 8;

#define GS(B, K0) do { \
    gload_lds16(A  + (size_t)(mt*128 + rA0)*K + (K0) + ko, &sA[B][0] + ldb0); \
    gload_lds16(A  + (size_t)(mt*128 + rA1)*K + (K0) + ko, &sA[B][0] + ldb1); \
    gload_lds16(Bt + (size_t)(nt*64  + rB )*K + (K0) + ko, &sB[B][0] + ldb0); \
  } while (0)

  GS(0, 0);
  int buf = 0;
  for (int k0 = 0; k0 < K; k0 += 32) {
    if (k0 + 32 < K) {
      GS(buf ^ 1, k0 + 32);
      asm volatile("s_waitcnt vmcnt(3)" ::: "memory");
    } else {
      asm volatile("s_waitcnt vmcnt(0)" ::: "memory");
    }
    __builtin_amdgcn_s_barrier();
    const __hip_bfloat16* pA = &sA[buf][0];
    const __hip_bfloat16* pB = &sB[buf][0];
    short8 af[4], bf[2];
    #pragma unroll
    for (int m = 0; m < 4; ++m) af[m] = *(const short8*)(pA + (wr*64 + m*16 + lr)*32 + lk);
    #pragma unroll
    for (int n = 0; n < 2; ++n) bf[n] = *(const short8*)(pB + (wc*32 + n*16 + lr)*32 + lk);
    __builtin_amdgcn_s_setprio(1);
    #pragma unroll
    for (int m = 0; m < 4; ++m)
      #pragma unroll
      for (int n = 0; n < 2; ++n)
        acc[m][n] = MFMA(af[m], bf[n], acc[m][n]);
    __builtin_amdgcn_s_setprio(0);
    __builtin_amdgcn_s_barrier();
    buf ^= 1;
  }
#undef GS
  int row0 = mt*128 + wr*64, col0 = nt*64 + wc*32;
  #pragma unroll
  for (int m = 0; m < 4; ++m)
    #pragma unroll
    for (int n = 0; n < 2; ++n)
      #pragma unroll
      for (int r = 0; r < 4; ++r) {
        int row = row0 + m*16 + (l >> 4)*4 + r;
        int col = col0 + n*16 + lr;
        store_out(&C[(size_t)row * N + col], acc[m][n][r]);
      }
}

// ---------------------------------------------------------------------------
// K5a: one-shot V transpose: vbuf [b*2048+s][h*64+d] -> vT [(b*16+h)*64+d][s].
// ---------------------------------------------------------------------------
__global__ __launch_bounds__(256) void vtrans_kernel(
    const __hip_bfloat16* __restrict__ vbuf, __hip_bfloat16* __restrict__ vT) {
  __shared__ __hip_bfloat16 tile[64][72];
  int bid = blockIdx.x;                 // b*512 + h*32 + st
  int b = bid >> 9, h = (bid >> 5) & 15, st = bid & 31;
  int t = threadIdx.x, j = t >> 2, c = t & 3;
  const short8* src = (const short8*)(vbuf + (size_t)(b*2048 + st*64 + j) * 1024 + h*64 + c*16);
  *(short8*)&tile[j][c*16]     = src[0];
  *(short8*)&tile[j][c*16 + 8] = src[1];
  __syncthreads();
  int d = t >> 2, c2 = t & 3;
  union { short8 s8[2]; __hip_bfloat16 hh[16]; } o;
  #pragma unroll
  for (int e = 0; e < 16; ++e) o.hh[e] = tile[c2*16 + e][d];
  short8* dst = (short8*)(vT + (size_t)((b*16 + h)*64 + d) * 2048 + st*64 + c2*16);
  dst[0] = o.s8[0];
  dst[1] = o.s8[1];
}

// ---------------------------------------------------------------------------
// K5b: flash attention v6.1 = R10 validated structure (140.5us), with exp ->
// exp2 (q pre-scaled by log2e in gemm_dual epilogue; THR = 8*log2e). P values
// mathematically identical; saves the v_mul inside every __expf lowering.
// ---------------------------------------------------------------------------
__global__ __launch_bounds__(256) void attn_kernel(
    const __hip_bfloat16* __restrict__ qk_h, const __hip_bfloat16* __restrict__ qk_l,
    const __hip_bfloat16* __restrict__ vT, __hip_bfloat16* __restrict__ ao) {
  __shared__ __align__(16) __hip_bfloat16 sKh[2][4096], sKl[2][4096], sVt[2][4096];
  __shared__ __align__(16) __hip_bfloat16 sP[4096];
  int t = threadIdx.x, w = t >> 6, l = t & 63, lr = l & 15, hi = l >> 4, lk = hi * 8;
  int bh = blockIdx.x & 31, qt = blockIdx.x >> 5;
  int b = bh >> 4, h = bh & 15;
  const __hip_bfloat16* qbh = qk_h + (size_t)b * 2048 * 2048 + h * 64;
  const __hip_bfloat16* qbl = qk_l + (size_t)b * 2048 * 2048 + h * 64;
  const __hip_bfloat16* kbh = qbh + 1024;
  const __hip_bfloat16* kbl = qbl + 1024;
  const __hip_bfloat16* vtb = vT + (size_t)bh * 64 * 2048;
  int qrow = qt*64 + w*16 + lr;
  short8 qh0 = *(const short8*)(qbh + (size_t)qrow*2048 + lk);
  short8 qh1 = *(const short8*)(qbh + (size_t)qrow*2048 + 32 + lk);
  short8 ql0 = *(const short8*)(qbl + (size_t)qrow*2048 + lk);
  short8 ql1 = *(const short8*)(qbl + (size_t)qrow*2048 + 32 + lk);
  f32x4 o_acc[4] = {};
  f32x4 l_acc = {0.f, 0.f, 0.f, 0.f};
  float m_run[4];
  #pragma unroll
  for (int r = 0; r < 4; ++r) m_run[r] = -1e30f;
  const short8 ones = {0x3F80, 0x3F80, 0x3F80, 0x3F80, 0x3F80, 0x3F80, 0x3F80, 0x3F80};
  const float THR = 8.f * LOG2E;          // defer-max threshold in log2 domain

  int swl = lr & 7;                       // read-side XOR swizzle key
  int c0e = (hi ^ swl) << 3;              // swizzled chunk offset, k 0..31 slice
  int c1e = c0e ^ 32;                     // k 32..63 slice
  int ci0 = t, ci1 = 256 + t;
  int r0 = ci0 >> 3, cs0 = (ci0 & 7) ^ (r0 & 7);
  int r1 = ci1 >> 3, cs1 = (ci1 & 7) ^ (r1 & 7);
  int ldb0 = (w*64) * 8, ldb1 = (256 + w*64) * 8;   // wave-uniform LDS bases

#define STAGE(B, KV) do { \
    gload_lds16(kbh + (size_t)((KV) + r0)*2048 + cs0*8, &sKh[B][0] + ldb0); \
    gload_lds16(kbh + (size_t)((KV) + r1)*2048 + cs1*8, &sKh[B][0] + ldb1); \
    gload_lds16(kbl + (size_t)((KV) + r0)*2048 + cs0*8, &sKl[B][0] + ldb0); \
    gload_lds16(kbl + (size_t)((KV) + r1)*2048 + cs1*8, &sKl[B][0] + ldb1); \
    gload_lds16(vtb + (size_t)r0*2048 + (KV) + cs0*8, &sVt[B][0] + ldb0); \
    gload_lds16(vtb + (size_t)r1*2048 + (KV) + cs1*8, &sVt[B][0] + ldb1); \
  } while (0)

  STAGE(0, 0);
  int buf = 0;
  for (int tile = 0; tile < 32; ++tile) {
    int kv0 = tile << 6;
    if (tile < 31) {
      STAGE(buf ^ 1, kv0 + 64);
      asm volatile("s_waitcnt vmcnt(6)" ::: "memory");  // cur tile landed; next 6 in flight
    } else {
      asm volatile("s_waitcnt vmcnt(0)" ::: "memory");
    }
    __builtin_amdgcn_s_barrier();
    const __hip_bfloat16* pKh = &sKh[buf][0];
    const __hip_bfloat16* pKl = &sKl[buf][0];
    const __hip_bfloat16* pVt = &sVt[buf][0];
    // QK^T: 16x64 logits per wave, split-bf16 3-pass (logits in log2 domain)
    f32x4 s_acc[4];
    __builtin_amdgcn_s_setprio(1);
    #pragma unroll
    for (int nf = 0; nf < 4; ++nf) {
      int rb = (nf*16 + lr) * 64;
      short8 kh0 = *(const short8*)(pKh + rb + c0e);
      short8 kh1 = *(const short8*)(pKh + rb + c1e);
      short8 kl0 = *(const short8*)(pKl + rb + c0e);
      short8 kl1 = *(const short8*)(pKl + rb + c1e);
      f32x4 sa = {};
      sa = MFMA(qh0, kh0, sa);
      sa = MFMA(qh1, kh1, sa);
      sa = MFMA(qh0, kl0, sa);
      sa = MFMA(qh1, kl1, sa);
      sa = MFMA(ql0, kh0, sa);
      sa = MFMA(ql1, kh1, sa);
      s_acc[nf] = sa;
    }
    __builtin_amdgcn_s_setprio(0);
    // ballot-gated lazy max: cheap detect, rare full rescale
    bool need = false;
    #pragma unroll
    for (int r = 0; r < 4; ++r) {
      float thr = m_run[r] + THR;
      #pragma unroll
      for (int nf = 0; nf < 4; ++nf) need |= (s_acc[nf][r] > thr);
    }
    if (__any(need)) {
      #pragma unroll
      for (int r = 0; r < 4; ++r) {
        float mx = fmaxf(fmaxf(s_acc[0][r], s_acc[1][r]), fmaxf(s_acc[2][r], s_acc[3][r]));
        #pragma unroll
        for (int msk = 1; msk < 16; msk <<= 1) mx = fmaxf(mx, __shfl_xor(mx, msk));
        float mnew = fmaxf(m_run[r], mx);
        float corr = exp2f(m_run[r] - mnew);   // == 1.0 exactly when mx <= m_run
        m_run[r] = mnew;
        l_acc[r] *= corr;
        #pragma unroll
        for (int df = 0; df < 4; ++df) o_acc[df][r] *= corr;
      }
    }
    // P = 2^(S - m_run), bf16, swizzled store to sP (conflict-free)
    #pragma unroll
    for (int r = 0; r < 4; ++r) {
      int prow = hi*4 + r;
      int pbase = (w << 10) + prow*64 + swl;
      #pragma unroll
      for (int nf = 0; nf < 4; ++nf) {
        float pv = exp2f(s_acc[nf][r] - m_run[r]);
        int chunk = (nf << 1) | (lr >> 3);
        sP[pbase + ((chunk ^ (prow & 7)) << 3)] = f2bf(pv);
      }
    }
    // PV: O[q][d] += P[q][kv] * Vt[d][kv];  l[q] += P[q][kv] * 1
    __builtin_amdgcn_s_setprio(1);
    #pragma unroll
    for (int kk = 0; kk < 2; ++kk) {
      int vck = (((kk << 2) | hi) ^ swl) << 3;
      short8 pf = *(const short8*)(sP + (w << 10) + lr*64 + vck);
      l_acc = MFMA(pf, ones, l_acc);
      #pragma unroll
      for (int df = 0; df < 4; ++df) {
        short8 vf = *(const short8*)(pVt + (df*16 + lr)*64 + vck);
        o_acc[df] = MFMA(pf, vf, o_acc[df]);
      }
    }
    __builtin_amdgcn_s_setprio(0);
    __builtin_amdgcn_s_barrier();     // all reads of buf done before next STAGE overwrites
    buf ^= 1;
  }
#undef STAGE
  size_t orow0 = (size_t)b*2048 + qt*64 + w*16 + hi*4;
  #pragma unroll
  for (int df = 0; df < 4; ++df)
    #pragma unroll
    for (int r = 0; r < 4; ++r) {
      float oval = o_acc[df][r] / l_acc[r];
      ao[(orow0 + r) * 1024 + h*64 + df*16 + lr] = f2bf(oval);
    }
}

// ---------------------------------------------------------------------------
// Workspace layout (68 MB total):
//   [ 0, 8)MB xh    -> ao after gemm_v (xh dead)
//   [ 8,16)MB xl    -> vbuf after gemm_dual (xl dead; vbuf dead after vtrans)
//   [16,32)MB qk_h
//   [32,48)MB qk_l
//   [48,52)MB Wqk_h
//   [52,56)MB Wqk_l
//   [56,58)MB Wv
//   [58,60)MB Wot
//   [60,68)MB vT
// ---------------------------------------------------------------------------
extern "C" void kernel_launch(void* const* d_in, const int* in_sizes, int n_in,
                              void* d_out, int out_size, void* d_ws, size_t ws_size,
                              hipStream_t stream) {
  const float* x   = (const float*)d_in[0];
  const float* lw  = (const float*)d_in[1];
  const float* lb  = (const float*)d_in[2];
  const float* Wq  = (const float*)d_in[3];
  const float* Wkv = (const float*)d_in[4];
  const float* qg  = (const float*)d_in[5];
  const float* kg  = (const float*)d_in[6];
  const float* Wo  = (const float*)d_in[7];
  float* out = (float*)d_out;
  char* ws = (char*)d_ws;
  const size_t MB = 1024 * 1024;
  __hip_bfloat16* xh    = (__hip_bfloat16*)(ws + 0);
  __hip_bfloat16* xl    = (__hip_bfloat16*)(ws + 8*MB);
  __hip_bfloat16* qk_h  = (__hip_bfloat16*)(ws + 16*MB);
  __hip_bfloat16* qk_l  = (__hip_bfloat16*)(ws + 32*MB);
  __hip_bfloat16* Wqk_h = (__hip_bfloat16*)(ws + 48*MB);
  __hip_bfloat16* Wqk_l = (__hip_bfloat16*)(ws + 52*MB);
  __hip_bfloat16* Wv    = (__hip_bfloat16*)(ws + 56*MB);
  __hip_bfloat16* Wot   = (__hip_bfloat16*)(ws + 58*MB);
  __hip_bfloat16* vT    = (__hip_bfloat16*)(ws + 60*MB);
  __hip_bfloat16* vbuf  = (__hip_bfloat16*)(ws + 8*MB);   // aliases xl (dead)
  __hip_bfloat16* ao    = (__hip_bfloat16*)(ws + 0);      // aliases xh (dead)

  ln_split_kernel<<<4096, 256, 0, stream>>>(x, lw, lb, xh, xl);
  wprep_kernel<<<1024, 256, 0, stream>>>(Wq, Wkv, Wo, Wqk_h, Wqk_l, Wv, Wot);
  gemm_dual_kernel<<<dim3(32, 16), 256, 0, stream>>>(xh, xl, Wqk_h, Wqk_l, qk_h, qk_l, qg, kg);
  gemm_single_kernel<__hip_bfloat16><<<dim3(32, 16), 256, 0, stream>>>(xh, Wv, vbuf, 1024);
  vtrans_kernel<<<1024, 256, 0, stream>>>(vbuf, vT);
  attn_kernel<<<1024, 256, 0, stream>>>(qk_h, qk_l, vT, ao);
  gemm_single_kernel<float><<<dim3(32, 16), 256, 0, stream>>>(ao, Wot, out, 1024);
}

// Round 12
// 312.021 us; speedup vs baseline: 1.0255x; 1.0255x over previous
//
#include <hip/hip_runtime.h>
#include <hip/hip_bf16.h>

#define DEVFN __device__ __forceinline__

typedef __attribute__((ext_vector_type(8))) short short8;
typedef __attribute__((ext_vector_type(4))) short short4v;
typedef __attribute__((ext_vector_type(4))) float f32x4;

#define MFMA(a,b,c) __builtin_amdgcn_mfma_f32_16x16x32_bf16((a),(b),(c),0,0,0)
#define LOG2E 1.4426950408889634f

DEVFN void gload_lds16(const __hip_bfloat16* g, __hip_bfloat16* l) {
  __builtin_amdgcn_global_load_lds((const __attribute__((address_space(1))) void*)g,
                                   (__attribute__((address_space(3))) void*)l, 16, 0, 0);
}

// HW 2^x: v_exp_f32 directly (exp2f without -ffast-math lowers to the slow
// __ocml_exp2_f32 libm call -- the R11 attn regression; this is 1 instr).
DEVFN float fast_exp2(float x) {
  float r;
  asm("v_exp_f32 %0, %1" : "=v"(r) : "v"(x));
  return r;
}

DEVFN float bf2f(__hip_bfloat16 h) { return __bfloat162float(h); }
DEVFN __hip_bfloat16 f2bf(float f) { return __float2bfloat16(f); }

DEVFN void store_out(float* p, float v) { *p = v; }
DEVFN void store_out(__hip_bfloat16* p, float v) { *p = f2bf(v); }

// ---------------------------------------------------------------------------
// K1: LayerNorm (fp32) -> xn split into bf16 hi + bf16 lo. One row per block.
// ---------------------------------------------------------------------------
__global__ __launch_bounds__(256) void ln_split_kernel(
    const float* __restrict__ x, const float* __restrict__ lw, const float* __restrict__ lb,
    __hip_bfloat16* __restrict__ xh, __hip_bfloat16* __restrict__ xl) {
  int row = blockIdx.x, t = threadIdx.x;
  float4 v = ((const float4*)(x + (size_t)row * 1024))[t];
  float s  = v.x + v.y + v.z + v.w;
  float ss = v.x*v.x + v.y*v.y + v.z*v.z + v.w*v.w;
  #pragma unroll
  for (int m = 1; m < 64; m <<= 1) { s += __shfl_xor(s, m); ss += __shfl_xor(ss, m); }
  __shared__ float red[8];
  int wv = t >> 6;
  if ((t & 63) == 0) { red[wv] = s; red[4 + wv] = ss; }
  __syncthreads();
  s  = red[0] + red[1] + red[2] + red[3];
  ss = red[4] + red[5] + red[6] + red[7];
  float mean = s * (1.f/1024.f);
  float var  = ss * (1.f/1024.f) - mean*mean;
  float inv  = rsqrtf(var + 1e-5f);
  float4 wv4 = ((const float4*)lw)[t];
  float4 bv4 = ((const float4*)lb)[t];
  float xv[4] = {v.x, v.y, v.z, v.w};
  float wa[4] = {wv4.x, wv4.y, wv4.z, wv4.w};
  float ba[4] = {bv4.x, bv4.y, bv4.z, bv4.w};
  union { short4v s4; __hip_bfloat16 h[4]; } uh, ul;
  #pragma unroll
  for (int j = 0; j < 4; ++j) {
    float val = (xv[j] - mean) * inv * wa[j] + ba[j];
    __hip_bfloat16 hi = f2bf(val);
    uh.h[j] = hi;
    ul.h[j] = f2bf(val - bf2f(hi));
  }
  ((short4v*)(xh + (size_t)row * 1024))[t] = uh.s4;
  ((short4v*)(xl + (size_t)row * 1024))[t] = ul.s4;
}

// ---------------------------------------------------------------------------
// K2: weight prep. Transpose fp32 [k][n] -> bf16 [n][k]; hi/lo split for Wq/Wk.
// ---------------------------------------------------------------------------
__global__ __launch_bounds__(256) void wprep_kernel(
    const float* __restrict__ Wq, const float* __restrict__ Wkv, const float* __restrict__ Wo,
    __hip_bfloat16* __restrict__ Wqk_h, __hip_bfloat16* __restrict__ Wqk_l,
    __hip_bfloat16* __restrict__ Wv, __hip_bfloat16* __restrict__ Wot) {
  __shared__ float tile[64][68];
  int bid = blockIdx.x, t = threadIdx.x;
  const float* src; int srcN, kt, nt, drow;
  __hip_bfloat16 *dh, *dl;
  if (bid < 256) {
    src = Wq; srcN = 1024; kt = bid >> 4; nt = bid & 15;
    dh = Wqk_h; dl = Wqk_l; drow = nt * 64;
  } else if (bid < 768) {
    int r = bid - 256; src = Wkv; srcN = 2048; kt = r >> 5; nt = r & 31;
    if (nt < 16) { dh = Wqk_h; dl = Wqk_l; drow = 1024 + nt * 64; }
    else         { dh = Wv;    dl = nullptr; drow = (nt - 16) * 64; }
  } else {
    int r = bid - 768; src = Wo; srcN = 1024; kt = r >> 4; nt = r & 15;
    dh = Wot; dl = nullptr; drow = nt * 64;
  }
  int lr = t >> 2, c = t & 3;
  const float* sp = src + (size_t)(kt*64 + lr) * srcN + nt*64 + c*16;
  float* tr = &tile[lr][c*16];
  ((float4*)tr)[0] = ((const float4*)sp)[0];
  ((float4*)tr)[1] = ((const float4*)sp)[1];
  ((float4*)tr)[2] = ((const float4*)sp)[2];
  ((float4*)tr)[3] = ((const float4*)sp)[3];
  __syncthreads();
  union { short8 s8[2]; __hip_bfloat16 h[16]; } hh, ll;
  #pragma unroll
  for (int e = 0; e < 16; ++e) {
    float wv = tile[c*16 + e][lr];
    __hip_bfloat16 hi = f2bf(wv);
    hh.h[e] = hi;
    ll.h[e] = f2bf(wv - bf2f(hi));
  }
  size_t doff = (size_t)(drow + lr) * 1024 + kt*64 + c*16;
  ((short8*)(dh + doff))[0] = hh.s8[0];
  ((short8*)(dh + doff))[1] = hh.s8[1];
  if (dl) {
    ((short8*)(dl + doff))[0] = ll.s8[0];
    ((short8*)(dl + doff))[1] = ll.s8[1];
  }
}

// ---------------------------------------------------------------------------
// K3: dual-precision GEMM (split-bf16, 3 MFMA) + fused per-head RMSNorm.
// 2-phase dbuf + counted vmcnt(8) + setprio (validated R11: GEMMs -20us).
// Q heads scaled by log2e so attn uses HW exp2 directly.
// ---------------------------------------------------------------------------
__global__ __launch_bounds__(256) void gemm_dual_kernel(
    const __hip_bfloat16* __restrict__ Ah, const __hip_bfloat16* __restrict__ Al,
    const __hip_bfloat16* __restrict__ Bh, const __hip_bfloat16* __restrict__ Bl,
    __hip_bfloat16* __restrict__ Ch, __hip_bfloat16* __restrict__ Cl,
    const float* __restrict__ qg, const float* __restrict__ kg) {
  __shared__ __align__(16) __hip_bfloat16 sAh[2][4096], sAl[2][4096], sBh[2][4096], sBl[2][4096];
  const int K = 1024, N = 2048;
  int mt = blockIdx.x, nt = blockIdx.y;
  int t = threadIdx.x, w = t >> 6, l = t & 63;
  int wr = w >> 1, wc = w & 1, lr = l & 15, lk = (l >> 4) * 8;
  f32x4 acc[4][4] = {};
  int r0 = t >> 2, r1 = 64 + (t >> 2), ko = (t & 3) * 8;
  int ldb0 = (w*64) * 8, ldb1 = (256 + w*64) * 8;

#define GSTAGE(B, K0) do { \
    gload_lds16(Ah + (size_t)(mt*128 + r0)*K + (K0) + ko, &sAh[B][0] + ldb0); \
    gload_lds16(Ah + (size_t)(mt*128 + r1)*K + (K0) + ko, &sAh[B][0] + ldb1); \
    gload_lds16(Al + (size_t)(mt*128 + r0)*K + (K0) + ko, &sAl[B][0] + ldb0); \
    gload_lds16(Al + (size_t)(mt*128 + r1)*K + (K0) + ko, &sAl[B][0] + ldb1); \
    gload_lds16(Bh + (size_t)(nt*128 + r0)*K + (K0) + ko, &sBh[B][0] + ldb0); \
    gload_lds16(Bh + (size_t)(nt*128 + r1)*K + (K0) + ko, &sBh[B][0] + ldb1); \
    gload_lds16(Bl + (size_t)(nt*128 + r0)*K + (K0) + ko, &sBl[B][0] + ldb0); \
    gload_lds16(Bl + (size_t)(nt*128 + r1)*K + (K0) + ko, &sBl[B][0] + ldb1); \
  } while (0)

  GSTAGE(0, 0);
  int buf = 0;
  for (int k0 = 0; k0 < K; k0 += 32) {
    if (k0 + 32 < K) {
      GSTAGE(buf ^ 1, k0 + 32);
      asm volatile("s_waitcnt vmcnt(8)" ::: "memory");  // retire cur tile; next 8 in flight
    } else {
      asm volatile("s_waitcnt vmcnt(0)" ::: "memory");
    }
    __builtin_amdgcn_s_barrier();
    const __hip_bfloat16* pAh = &sAh[buf][0];
    const __hip_bfloat16* pAl = &sAl[buf][0];
    const __hip_bfloat16* pBh = &sBh[buf][0];
    const __hip_bfloat16* pBl = &sBl[buf][0];
    short8 ah[4], al[4], bh[4], bl[4];
    #pragma unroll
    for (int m = 0; m < 4; ++m) {
      int ro = (wr*64 + m*16 + lr)*32 + lk;
      ah[m] = *(const short8*)(pAh + ro);
      al[m] = *(const short8*)(pAl + ro);
    }
    #pragma unroll
    for (int n = 0; n < 4; ++n) {
      int ro = (wc*64 + n*16 + lr)*32 + lk;
      bh[n] = *(const short8*)(pBh + ro);
      bl[n] = *(const short8*)(pBl + ro);
    }
    __builtin_amdgcn_s_setprio(1);
    #pragma unroll
    for (int m = 0; m < 4; ++m)
      #pragma unroll
      for (int n = 0; n < 4; ++n) {
        acc[m][n] = MFMA(ah[m], bh[n], acc[m][n]);
        acc[m][n] = MFMA(ah[m], bl[n], acc[m][n]);
        acc[m][n] = MFMA(al[m], bh[n], acc[m][n]);
      }
    __builtin_amdgcn_s_setprio(0);
    __builtin_amdgcn_s_barrier();
    buf ^= 1;
  }
#undef GSTAGE
  int col0 = nt*128 + wc*64;
  int head = col0 >> 6;
  const float* gamma = (head < 16) ? (qg + head*64) : (kg + (head - 16)*64);
  float qscale = (head < 16) ? LOG2E : 1.0f;   // fold log2e into q for exp2 attn
  float g[4];
  #pragma unroll
  for (int nf = 0; nf < 4; ++nf) g[nf] = gamma[nf*16 + lr];
  #pragma unroll
  for (int m = 0; m < 4; ++m) {
    #pragma unroll
    for (int r = 0; r < 4; ++r) {
      float ss2 = 0.f;
      #pragma unroll
      for (int nf = 0; nf < 4; ++nf) ss2 += acc[m][nf][r] * acc[m][nf][r];
      #pragma unroll
      for (int msk = 1; msk < 16; msk <<= 1) ss2 += __shfl_xor(ss2, msk);
      float scl = rsqrtf(ss2 * (1.f/64.f) + 1e-8f) * 8.f * qscale;
      int row = mt*128 + wr*64 + m*16 + (l >> 4)*4 + r;
      #pragma unroll
      for (int nf = 0; nf < 4; ++nf) {
        float val = acc[m][nf][r] * scl * g[nf];
        __hip_bfloat16 hi = f2bf(val);
        size_t off = (size_t)row * N + col0 + nf*16 + lr;
        Ch[off] = hi;
        Cl[off] = f2bf(val - bf2f(hi));
      }
    }
  }
}

// ---------------------------------------------------------------------------
// K4/K6: single-precision bf16 GEMM — BM=128, BN=64, 2-phase dbuf + vmcnt(3)
// + setprio; grid 512 = 2 blocks/CU (validated R11).
// ---------------------------------------------------------------------------
template <typename OUT_T>
__global__ __launch_bounds__(256) void gemm_single_kernel(
    const __hip_bfloat16* __restrict__ A, const __hip_bfloat16* __restrict__ Bt,
    OUT_T* __restrict__ C, int N) {
  __shared__ __align__(16) __hip_bfloat16 sA[2][4096], sB[2][2048];
  const int K = 1024;
  int mt = blockIdx.x, nt = blockIdx.y;
  int t = threadIdx.x, w = t >> 6, l = t & 63;
  int wr = w >> 1, wc = w & 1, lr = l & 15, lk = (l >> 4) * 8;
  f32x4 acc[4][2] = {};
  int rA0 = t >> 2, rA1 = 64 + (t >> 2), rB = t >> 2, ko = (t & 3) * 8;
  int ldb0 = (w*64) * 8, ldb1 = (256 + w*64) * 8;

#define GS(B, K0) do { \
    gload_lds16(A  + (size_t)(mt*128 + rA0)*K + (K0) + ko, &sA[B][0] + ldb0); \
    gload_lds16(A  + (size_t)(mt*128 + rA1)*K + (K0) + ko, &sA[B][0] + ldb1); \
    gload_lds16(Bt + (size_t)(nt*64  + rB )*K + (K0) + ko, &sB[B][0] + ldb0); \
  } while (0)

  GS(0, 0);
  int buf = 0;
  for (int k0 = 0; k0 < K; k0 += 32) {
    if (k0 + 32 < K) {
      GS(buf ^ 1, k0 + 32);
      asm volatile("s_waitcnt vmcnt(3)" ::: "memory");
    } else {
      asm volatile("s_waitcnt vmcnt(0)" ::: "memory");
    }
    __builtin_amdgcn_s_barrier();
    const __hip_bfloat16* pA = &sA[buf][0];
    const __hip_bfloat16* pB = &sB[buf][0];
    short8 af[4], bf[2];
    #pragma unroll
    for (int m = 0; m < 4; ++m) af[m] = *(const short8*)(pA + (wr*64 + m*16 + lr)*32 + lk);
    #pragma unroll
    for (int n = 0; n < 2; ++n) bf[n] = *(const short8*)(pB + (wc*32 + n*16 + lr)*32 + lk);
    __builtin_amdgcn_s_setprio(1);
    #pragma unroll
    for (int m = 0; m < 4; ++m)
      #pragma unroll
      for (int n = 0; n < 2; ++n)
        acc[m][n] = MFMA(af[m], bf[n], acc[m][n]);
    __builtin_amdgcn_s_setprio(0);
    __builtin_amdgcn_s_barrier();
    buf ^= 1;
  }
#undef GS
  int row0 = mt*128 + wr*64, col0 = nt*64 + wc*32;
  #pragma unroll
  for (int m = 0; m < 4; ++m)
    #pragma unroll
    for (int n = 0; n < 2; ++n)
      #pragma unroll
      for (int r = 0; r < 4; ++r) {
        int row = row0 + m*16 + (l >> 4)*4 + r;
        int col = col0 + n*16 + lr;
        store_out(&C[(size_t)row * N + col], acc[m][n][r]);
      }
}

// ---------------------------------------------------------------------------
// K5a: one-shot V transpose: vbuf [b*2048+s][h*64+d] -> vT [(b*16+h)*64+d][s].
// ---------------------------------------------------------------------------
__global__ __launch_bounds__(256) void vtrans_kernel(
    const __hip_bfloat16* __restrict__ vbuf, __hip_bfloat16* __restrict__ vT) {
  __shared__ __hip_bfloat16 tile[64][72];
  int bid = blockIdx.x;                 // b*512 + h*32 + st
  int b = bid >> 9, h = (bid >> 5) & 15, st = bid & 31;
  int t = threadIdx.x, j = t >> 2, c = t & 3;
  const short8* src = (const short8*)(vbuf + (size_t)(b*2048 + st*64 + j) * 1024 + h*64 + c*16);
  *(short8*)&tile[j][c*16]     = src[0];
  *(short8*)&tile[j][c*16 + 8] = src[1];
  __syncthreads();
  int d = t >> 2, c2 = t & 3;
  union { short8 s8[2]; __hip_bfloat16 hh[16]; } o;
  #pragma unroll
  for (int e = 0; e < 16; ++e) o.hh[e] = tile[c2*16 + e][d];
  short8* dst = (short8*)(vT + (size_t)((b*16 + h)*64 + d) * 2048 + st*64 + c2*16);
  dst[0] = o.s8[0];
  dst[1] = o.s8[1];
}

// ---------------------------------------------------------------------------
// K5b: flash attention v6.2 = R10 structure + log2-domain softmax with HW
// v_exp_f32 (R11's exp2f hit the slow __ocml_exp2_f32 libm path -- the +20us
// regression; fast_exp2 is the 1-instruction fix).
// ---------------------------------------------------------------------------
__global__ __launch_bounds__(256) void attn_kernel(
    const __hip_bfloat16* __restrict__ qk_h, const __hip_bfloat16* __restrict__ qk_l,
    const __hip_bfloat16* __restrict__ vT, __hip_bfloat16* __restrict__ ao) {
  __shared__ __align__(16) __hip_bfloat16 sKh[2][4096], sKl[2][4096], sVt[2][4096];
  __shared__ __align__(16) __hip_bfloat16 sP[4096];
  int t = threadIdx.x, w = t >> 6, l = t & 63, lr = l & 15, hi = l >> 4, lk = hi * 8;
  int bh = blockIdx.x & 31, qt = blockIdx.x >> 5;
  int b = bh >> 4, h = bh & 15;
  const __hip_bfloat16* qbh = qk_h + (size_t)b * 2048 * 2048 + h * 64;
  const __hip_bfloat16* qbl = qk_l + (size_t)b * 2048 * 2048 + h * 64;
  const __hip_bfloat16* kbh = qbh + 1024;
  const __hip_bfloat16* kbl = qbl + 1024;
  const __hip_bfloat16* vtb = vT + (size_t)bh * 64 * 2048;
  int qrow = qt*64 + w*16 + lr;
  short8 qh0 = *(const short8*)(qbh + (size_t)qrow*2048 + lk);
  short8 qh1 = *(const short8*)(qbh + (size_t)qrow*2048 + 32 + lk);
  short8 ql0 = *(const short8*)(qbl + (size_t)qrow*2048 + lk);
  short8 ql1 = *(const short8*)(qbl + (size_t)qrow*2048 + 32 + lk);
  f32x4 o_acc[4] = {};
  f32x4 l_acc = {0.f, 0.f, 0.f, 0.f};
  float m_run[4];
  #pragma unroll
  for (int r = 0; r < 4; ++r) m_run[r] = -1e30f;
  const short8 ones = {0x3F80, 0x3F80, 0x3F80, 0x3F80, 0x3F80, 0x3F80, 0x3F80, 0x3F80};
  const float THR = 8.f * LOG2E;          // defer-max threshold in log2 domain

  int swl = lr & 7;                       // read-side XOR swizzle key
  int c0e = (hi ^ swl) << 3;              // swizzled chunk offset, k 0..31 slice
  int c1e = c0e ^ 32;                     // k 32..63 slice
  int ci0 = t, ci1 = 256 + t;
  int r0 = ci0 >> 3, cs0 = (ci0 & 7) ^ (r0 & 7);
  int r1 = ci1 >> 3, cs1 = (ci1 & 7) ^ (r1 & 7);
  int ldb0 = (w*64) * 8, ldb1 = (256 + w*64) * 8;   // wave-uniform LDS bases

#define STAGE(B, KV) do { \
    gload_lds16(kbh + (size_t)((KV) + r0)*2048 + cs0*8, &sKh[B][0] + ldb0); \
    gload_lds16(kbh + (size_t)((KV) + r1)*2048 + cs1*8, &sKh[B][0] + ldb1); \
    gload_lds16(kbl + (size_t)((KV) + r0)*2048 + cs0*8, &sKl[B][0] + ldb0); \
    gload_lds16(kbl + (size_t)((KV) + r1)*2048 + cs1*8, &sKl[B][0] + ldb1); \
    gload_lds16(vtb + (size_t)r0*2048 + (KV) + cs0*8, &sVt[B][0] + ldb0); \
    gload_lds16(vtb + (size_t)r1*2048 + (KV) + cs1*8, &sVt[B][0] + ldb1); \
  } while (0)

  STAGE(0, 0);
  int buf = 0;
  for (int tile = 0; tile < 32; ++tile) {
    int kv0 = tile << 6;
    if (tile < 31) {
      STAGE(buf ^ 1, kv0 + 64);
      asm volatile("s_waitcnt vmcnt(6)" ::: "memory");  // cur tile landed; next 6 in flight
    } else {
      asm volatile("s_waitcnt vmcnt(0)" ::: "memory");
    }
    __builtin_amdgcn_s_barrier();
    const __hip_bfloat16* pKh = &sKh[buf][0];
    const __hip_bfloat16* pKl = &sKl[buf][0];
    const __hip_bfloat16* pVt = &sVt[buf][0];
    // QK^T: 16x64 logits per wave, split-bf16 3-pass (logits in log2 domain)
    f32x4 s_acc[4];
    __builtin_amdgcn_s_setprio(1);
    #pragma unroll
    for (int nf = 0; nf < 4; ++nf) {
      int rb = (nf*16 + lr) * 64;
      short8 kh0 = *(const short8*)(pKh + rb + c0e);
      short8 kh1 = *(const short8*)(pKh + rb + c1e);
      short8 kl0 = *(const short8*)(pKl + rb + c0e);
      short8 kl1 = *(const short8*)(pKl + rb + c1e);
      f32x4 sa = {};
      sa = MFMA(qh0, kh0, sa);
      sa = MFMA(qh1, kh1, sa);
      sa = MFMA(qh0, kl0, sa);
      sa = MFMA(qh1, kl1, sa);
      sa = MFMA(ql0, kh0, sa);
      sa = MFMA(ql1, kh1, sa);
      s_acc[nf] = sa;
    }
    __builtin_amdgcn_s_setprio(0);
    // ballot-gated lazy max: cheap detect, rare full rescale
    bool need = false;
    #pragma unroll
    for (int r = 0; r < 4; ++r) {
      float thr = m_run[r] + THR;
      #pragma unroll
      for (int nf = 0; nf < 4; ++nf) need |= (s_acc[nf][r] > thr);
    }
    if (__any(need)) {
      #pragma unroll
      for (int r = 0; r < 4; ++r) {
        float mx = fmaxf(fmaxf(s_acc[0][r], s_acc[1][r]), fmaxf(s_acc[2][r], s_acc[3][r]));
        #pragma unroll
        for (int msk = 1; msk < 16; msk <<= 1) mx = fmaxf(mx, __shfl_xor(mx, msk));
        float mnew = fmaxf(m_run[r], mx);
        float corr = fast_exp2(m_run[r] - mnew);   // == 1.0 exactly when mx <= m_run
        m_run[r] = mnew;
        l_acc[r] *= corr;
        #pragma unroll
        for (int df = 0; df < 4; ++df) o_acc[df][r] *= corr;
      }
    }
    // P = 2^(S - m_run), bf16, swizzled store to sP (conflict-free)
    #pragma unroll
    for (int r = 0; r < 4; ++r) {
      int prow = hi*4 + r;
      int pbase = (w << 10) + prow*64 + swl;
      #pragma unroll
      for (int nf = 0; nf < 4; ++nf) {
        float pv = fast_exp2(s_acc[nf][r] - m_run[r]);
        int chunk = (nf << 1) | (lr >> 3);
        sP[pbase + ((chunk ^ (prow & 7)) << 3)] = f2bf(pv);
      }
    }
    // PV: O[q][d] += P[q][kv] * Vt[d][kv];  l[q] += P[q][kv] * 1
    __builtin_amdgcn_s_setprio(1);
    #pragma unroll
    for (int kk = 0; kk < 2; ++kk) {
      int vck = (((kk << 2) | hi) ^ swl) << 3;
      short8 pf = *(const short8*)(sP + (w << 10) + lr*64 + vck);
      l_acc = MFMA(pf, ones, l_acc);
      #pragma unroll
      for (int df = 0; df < 4; ++df) {
        short8 vf = *(const short8*)(pVt + (df*16 + lr)*64 + vck);
        o_acc[df] = MFMA(pf, vf, o_acc[df]);
      }
    }
    __builtin_amdgcn_s_setprio(0);
    __builtin_amdgcn_s_barrier();     // all reads of buf done before next STAGE overwrites
    buf ^= 1;
  }
#undef STAGE
  size_t orow0 = (size_t)b*2048 + qt*64 + w*16 + hi*4;
  #pragma unroll
  for (int df = 0; df < 4; ++df)
    #pragma unroll
    for (int r = 0; r < 4; ++r) {
      float oval = o_acc[df][r] / l_acc[r];
      ao[(orow0 + r) * 1024 + h*64 + df*16 + lr] = f2bf(oval);
    }
}

// ---------------------------------------------------------------------------
// Workspace layout (68 MB total):
//   [ 0, 8)MB xh    -> ao after gemm_v (xh dead)
//   [ 8,16)MB xl    -> vbuf after gemm_dual (xl dead; vbuf dead after vtrans)
//   [16,32)MB qk_h
//   [32,48)MB qk_l
//   [48,52)MB Wqk_h
//   [52,56)MB Wqk_l
//   [56,58)MB Wv
//   [58,60)MB Wot
//   [60,68)MB vT
// ---------------------------------------------------------------------------
extern "C" void kernel_launch(void* const* d_in, const int* in_sizes, int n_in,
                              void* d_out, int out_size, void* d_ws, size_t ws_size,
                              hipStream_t stream) {
  const float* x   = (const float*)d_in[0];
  const float* lw  = (const float*)d_in[1];
  const float* lb  = (const float*)d_in[2];
  const float* Wq  = (const float*)d_in[3];
  const float* Wkv = (const float*)d_in[4];
  const float* qg  = (const float*)d_in[5];
  const float* kg  = (const float*)d_in[6];
  const float* Wo  = (const float*)d_in[7];
  float* out = (float*)d_out;
  char* ws = (char*)d_ws;
  const size_t MB = 1024 * 1024;
  __hip_bfloat16* xh    = (__hip_bfloat16*)(ws + 0);
  __hip_bfloat16* xl    = (__hip_bfloat16*)(ws + 8*MB);
  __hip_bfloat16* qk_h  = (__hip_bfloat16*)(ws + 16*MB);
  __hip_bfloat16* qk_l  = (__hip_bfloat16*)(ws + 32*MB);
  __hip_bfloat16* Wqk_h = (__hip_bfloat16*)(ws + 48*MB);
  __hip_bfloat16* Wqk_l = (__hip_bfloat16*)(ws + 52*MB);
  __hip_bfloat16* Wv    = (__hip_bfloat16*)(ws + 56*MB);
  __hip_bfloat16* Wot   = (__hip_bfloat16*)(ws + 58*MB);
  __hip_bfloat16* vT    = (__hip_bfloat16*)(ws + 60*MB);
  __hip_bfloat16* vbuf  = (__hip_bfloat16*)(ws + 8*MB);   // aliases xl (dead)
  __hip_bfloat16* ao    = (__hip_bfloat16*)(ws + 0);      // aliases xh (dead)

  ln_split_kernel<<<4096, 256, 0, stream>>>(x, lw, lb, xh, xl);
  wprep_kernel<<<1024, 256, 0, stream>>>(Wq, Wkv, Wo, Wqk_h, Wqk_l, Wv, Wot);
  gemm_dual_kernel<<<dim3(32, 16), 256, 0, stream>>>(xh, xl, Wqk_h, Wqk_l, qk_h, qk_l, qg, kg);
  gemm_single_kernel<__hip_bfloat16><<<dim3(32, 16), 256, 0, stream>>>(xh, Wv, vbuf, 1024);
  vtrans_kernel<<<1024, 256, 0, stream>>>(vbuf, vT);
  attn_kernel<<<1024, 256, 0, stream>>>(qk_h, qk_l, vT, ao);
  gemm_single_kernel<float><<<dim3(32, 16), 256, 0, stream>>>(ao, Wot, out, 1024);
}